// Round 8
// baseline (996.770 us; speedup 1.0000x reference)
//
#include <hip/hip_runtime.h>
#include <hip/hip_bf16.h>

// MoE: T=2048, H=2048, I=5632, E=8, top-2 renormalized.
// route -> per-expert lists -> cvt x to bf16 (scratch = d_out) -> grouped GEMM1
// (x@w1^T fused SwiGLU, bf16 h to ws) -> memset out -> grouped GEMM2 (h@w2^T, *w, atomicAdd).
// R8: R3's proven 2-buffer structure + XCD-aware work remap (T1): work order
// (expert, n-panel, m-tile) with m-tile fastest, wid=(bid%8)*(nwg/8)+bid/8 ->
// each XCD owns one expert; 16 consecutive blocks share one weight panel in its L2.
// Lessons: launch_bounds tighter than (256,2) spills (R4/R5); deep pipelines bought
// nothing (R6/R7) because the cost was HBM-miss latency, not schedule.

#define TT 2048
#define HH 2048
#define II 5632
#define NE 8

using f32x4  = __attribute__((ext_vector_type(4))) float;
using bf16x8 = __attribute__((ext_vector_type(8))) short;

__device__ __forceinline__ uint32_t bfbits(float f) {
    __hip_bfloat16 h = __float2bfloat16(f);
    unsigned short u;
    __builtin_memcpy(&u, &h, 2);
    return (uint32_t)u;
}
__device__ __forceinline__ uint32_t pk2(float a, float b) {
    return bfbits(a) | (bfbits(b) << 16);
}
__device__ __forceinline__ uint4 pk8(const float4& a, const float4& b) {
    uint4 r;
    r.x = pk2(a.x, a.y); r.y = pk2(a.z, a.w);
    r.z = pk2(b.x, b.y); r.w = pk2(b.z, b.w);
    return r;
}

// ---------------- x -> bf16 ----------------
__global__ void cvt_x(const float* __restrict__ x, __hip_bfloat16* __restrict__ xb) {
    const int i = (blockIdx.x * 256 + threadIdx.x) * 8;
    float4 a = *(const float4*)(x + i);
    float4 b = *(const float4*)(x + i + 4);
    *(uint4*)(xb + i) = pk8(a, b);
}

// ---------------- routing ----------------
__global__ void route_topk(const float* __restrict__ gating,
                           int* __restrict__ tk_idx, float* __restrict__ tk_w) {
    int t = blockIdx.x * 256 + threadIdx.x;
    if (t >= TT) return;
    float g[NE];
#pragma unroll
    for (int e = 0; e < NE; e++) g[e] = gating[t * NE + e];
    int i0 = 0; float b0 = g[0];
#pragma unroll
    for (int e = 1; e < NE; e++) if (g[e] > b0) { b0 = g[e]; i0 = e; }
    int i1 = (i0 == 0) ? 1 : 0; float b1 = g[i1];
#pragma unroll
    for (int e = 0; e < NE; e++) if (e != i0 && g[e] > b1) { b1 = g[e]; i1 = e; }
    float ex = expf(b1 - b0);
    float w0 = 1.f / (1.f + ex);
    float w1 = ex / (1.f + ex);
    tk_idx[2 * t] = i0; tk_idx[2 * t + 1] = i1;
    tk_w[2 * t] = w0;  tk_w[2 * t + 1] = w1;
}

__global__ void build_lists(const int* __restrict__ tk_idx, const float* __restrict__ tk_w,
                            int* __restrict__ list_tok, float* __restrict__ list_w,
                            int* __restrict__ counts) {
    const int e = blockIdx.x;
    const int tid = threadIdx.x;
    int flag[8]; float wt[8];
    int cnt = 0;
#pragma unroll
    for (int j = 0; j < 8; j++) {
        int t = tid * 8 + j;
        int f = -1;
        if (tk_idx[2 * t] == e) f = 0;
        else if (tk_idx[2 * t + 1] == e) f = 1;
        flag[j] = f;
        wt[j] = (f >= 0) ? tk_w[2 * t + f] : 0.f;
        cnt += (f >= 0) ? 1 : 0;
    }
    __shared__ int s[256];
    s[tid] = cnt;
    __syncthreads();
    for (int d = 1; d < 256; d <<= 1) {
        int v = (tid >= d) ? s[tid - d] : 0;
        __syncthreads();
        s[tid] += v;
        __syncthreads();
    }
    int pos = s[tid] - cnt;
#pragma unroll
    for (int j = 0; j < 8; j++) {
        if (flag[j] >= 0) {
            list_tok[e * TT + pos] = tid * 8 + j;
            list_w[e * TT + pos] = wt[j];
            pos++;
        }
    }
    if (tid == 255) counts[e] = s[255];
}

// ---------------- GEMM1: h = SwiGLU(Xe @ w1[e]^T), tile 128(M) x 64(N of I), BK=32 ----------------
__global__ __launch_bounds__(256, 2) void gemm1_swiglu(
    const __hip_bfloat16* __restrict__ xb, const float* __restrict__ w1,
    const int* __restrict__ list_tok, const int* __restrict__ counts,
    __hip_bfloat16* __restrict__ hbuf) {
    // XCD-aware remap: nwg = 88*128 = 11264; 11264/8 = 1408 = one expert (88 n x 16 mt).
    // work id wid = (bid%8)*1408 + bid/8 ; decode (e, n, mt) with mt fastest.
    const int bid = blockIdx.y * 88 + blockIdx.x;
    const int wid = (bid & 7) * 1408 + (bid >> 3);
    const int e   = wid / 1408;
    const int rem = wid - e * 1408;
    const int n0  = (rem >> 4) * 64;
    const int mt  = rem & 15;

    const int cnt = counts[e];
    const int row0 = mt * 128;
    if (row0 >= cnt) return;
    int off = 0;
#pragma unroll
    for (int i = 0; i < NE; i++) if (i < e) off += counts[i];
    const int valid = min(128, cnt - row0);
    const int tid = threadIdx.x;

    __shared__ uint4 As[2][512];   // 128 rows x 32 bf16 (4 x 16B slots/row), swizzled
    __shared__ uint4 Bg[2][256];   // 64 x 32
    __shared__ uint4 Bu[2][256];

    const int ar0 = tid >> 2, au = tid & 3;
    const int ar1 = ar0 + 64;
    const int tokA0 = list_tok[e * TT + row0 + min(ar0, valid - 1)];
    const int tokA1 = list_tok[e * TT + row0 + min(ar1, valid - 1)];
    const __hip_bfloat16* aS0 = xb + (size_t)tokA0 * HH + au * 8;
    const __hip_bfloat16* aS1 = xb + (size_t)tokA1 * HH + au * 8;
    const float* gS = w1 + (size_t)e * (2 * II) * HH + (size_t)(n0 + ar0) * HH + au * 8;
    const float* uS = gS + (size_t)II * HH;
    const int awi0 = ar0 * 4 + (au ^ ((ar0 >> 1) & 3));
    const int awi1 = ar1 * 4 + (au ^ ((ar1 >> 1) & 3));
    const int bwi  = ar0 * 4 + (au ^ ((ar0 >> 1) & 3));

    uint4 rA0, rA1; float4 rGa, rGb, rUa, rUb;
    auto LOAD = [&](int kt) {
        const int k = kt * 32;
        rGa  = *(const float4*)(gS + k);  rGb  = *(const float4*)(gS + k + 4);
        rUa  = *(const float4*)(uS + k);  rUb  = *(const float4*)(uS + k + 4);
        rA0  = *(const uint4*)(aS0 + k);
        rA1  = *(const uint4*)(aS1 + k);
    };
    auto STORE = [&](int b) {
        As[b][awi0] = rA0;
        As[b][awi1] = rA1;
        Bg[b][bwi]  = pk8(rGa, rGb);
        Bu[b][bwi]  = pk8(rUa, rUb);
    };

    // fragment indices: wave grid 2x2, wave tile 64(M) x 32(N)
    const int lane = tid & 63;
    const int wv = tid >> 6;
    const int wm = wv >> 1, wn = wv & 1;
    const int l15 = lane & 15, ks = lane >> 4;
    int aidx[4], bidx[2];
#pragma unroll
    for (int m = 0; m < 4; m++) { int r = wm * 64 + m * 16 + l15; aidx[m] = r * 4 + (ks ^ ((r >> 1) & 3)); }
#pragma unroll
    for (int n = 0; n < 2; n++) { int c = wn * 32 + n * 16 + l15; bidx[n] = c * 4 + (ks ^ ((c >> 1) & 3)); }

    f32x4 accg[4][2], accu[4][2];
#pragma unroll
    for (int m = 0; m < 4; m++)
#pragma unroll
        for (int n = 0; n < 2; n++) { accg[m][n] = 0; accu[m][n] = 0; }

    LOAD(0); STORE(0); __syncthreads();
    const int KT = HH / 32;  // 64
#pragma unroll 2
    for (int kt = 0; kt < KT; ++kt) {
        const int cur = kt & 1;
        if (kt + 1 < KT) LOAD(kt + 1);
        bf16x8 af[4], gf[2], uf[2];
#pragma unroll
        for (int m = 0; m < 4; m++) { uint4 t = As[cur][aidx[m]]; af[m] = __builtin_bit_cast(bf16x8, t); }
#pragma unroll
        for (int n = 0; n < 2; n++) {
            uint4 t = Bg[cur][bidx[n]]; gf[n] = __builtin_bit_cast(bf16x8, t);
            uint4 t2 = Bu[cur][bidx[n]]; uf[n] = __builtin_bit_cast(bf16x8, t2);
        }
#pragma unroll
        for (int m = 0; m < 4; m++)
#pragma unroll
            for (int n = 0; n < 2; n++) {
                accg[m][n] = __builtin_amdgcn_mfma_f32_16x16x32_bf16(af[m], gf[n], accg[m][n], 0, 0, 0);
                accu[m][n] = __builtin_amdgcn_mfma_f32_16x16x32_bf16(af[m], uf[n], accu[m][n], 0, 0, 0);
            }
        if (kt + 1 < KT) STORE(cur ^ 1);
        __syncthreads();
    }

    // epilogue: h = silu(g)*u -> bf16
#pragma unroll
    for (int m = 0; m < 4; m++) {
#pragma unroll
        for (int r = 0; r < 4; r++) {
            const int lr = wm * 64 + m * 16 + ks * 4 + r;   // C row = (lane>>4)*4 + reg
            if (lr < valid) {
                __hip_bfloat16* hrow = hbuf + (size_t)(off + row0 + lr) * II;
#pragma unroll
                for (int n = 0; n < 2; n++) {
                    const int col = n0 + wn * 32 + n * 16 + l15;   // C col = lane&15
                    float g = accg[m][n][r], u = accu[m][n][r];
                    float h = g / (1.f + __expf(-g)) * u;
                    hrow[col] = __float2bfloat16(h);
                }
            }
        }
    }
}

// ---------------- GEMM2: out += (h @ w2[e]^T) * route_w, tile 128x128, BK=32 ----------------
__global__ __launch_bounds__(256, 2) void gemm2_scatter(
    const __hip_bfloat16* __restrict__ hbuf, const float* __restrict__ w2,
    const int* __restrict__ list_tok, const float* __restrict__ list_w,
    const int* __restrict__ counts, float* __restrict__ out) {
    // XCD-aware remap: nwg = 16*128 = 2048; 2048/8 = 256 = one expert (16 n x 16 mt).
    const int bid = blockIdx.y * 16 + blockIdx.x;
    const int wid = (bid & 7) * 256 + (bid >> 3);
    const int e   = wid >> 8;
    const int rem = wid & 255;
    const int n0  = (rem >> 4) * 128;
    const int mt  = rem & 15;

    const int cnt = counts[e];
    const int row0 = mt * 128;
    if (row0 >= cnt) return;
    int off = 0;
#pragma unroll
    for (int i = 0; i < NE; i++) if (i < e) off += counts[i];
    const int valid = min(128, cnt - row0);
    const int tid = threadIdx.x;

    __shared__ uint4 As[2][512];
    __shared__ uint4 Bs[2][512];

    const int ar0 = tid >> 2, au = tid & 3;
    const int ar1 = ar0 + 64;
    const size_t hr0 = (size_t)(off + row0 + min(ar0, valid - 1)) * II + au * 8;
    const size_t hr1 = (size_t)(off + row0 + min(ar1, valid - 1)) * II + au * 8;
    const float* bS0 = w2 + (size_t)e * HH * II + (size_t)(n0 + ar0) * II + au * 8;
    const float* bS1 = bS0 + (size_t)64 * II;
    const int awi0 = ar0 * 4 + (au ^ ((ar0 >> 1) & 3));
    const int awi1 = ar1 * 4 + (au ^ ((ar1 >> 1) & 3));

    uint4 rA0, rA1; float4 rB0a, rB0b, rB1a, rB1b;
    auto LOAD = [&](int kt) {
        const int k = kt * 32;
        rB0a = *(const float4*)(bS0 + k); rB0b = *(const float4*)(bS0 + k + 4);
        rB1a = *(const float4*)(bS1 + k); rB1b = *(const float4*)(bS1 + k + 4);
        rA0 = *(const uint4*)(hbuf + hr0 + k);
        rA1 = *(const uint4*)(hbuf + hr1 + k);
    };
    auto STORE = [&](int b) {
        As[b][awi0] = rA0;
        As[b][awi1] = rA1;
        Bs[b][awi0] = pk8(rB0a, rB0b);
        Bs[b][awi1] = pk8(rB1a, rB1b);
    };

    // wave tile 64x64
    const int lane = tid & 63;
    const int wv = tid >> 6;
    const int wm = wv >> 1, wn = wv & 1;
    const int l15 = lane & 15, ks = lane >> 4;
    int aidx[4], bidx[4];
#pragma unroll
    for (int m = 0; m < 4; m++) { int r = wm * 64 + m * 16 + l15; aidx[m] = r * 4 + (ks ^ ((r >> 1) & 3)); }
#pragma unroll
    for (int n = 0; n < 4; n++) { int c = wn * 64 + n * 16 + l15; bidx[n] = c * 4 + (ks ^ ((c >> 1) & 3)); }

    f32x4 acc[4][4];
#pragma unroll
    for (int m = 0; m < 4; m++)
#pragma unroll
        for (int n = 0; n < 4; n++) acc[m][n] = 0;

    LOAD(0); STORE(0); __syncthreads();
    const int KT = II / 32;  // 176
#pragma unroll 2
    for (int kt = 0; kt < KT; ++kt) {
        const int cur = kt & 1;
        if (kt + 1 < KT) LOAD(kt + 1);
        bf16x8 af[4], bf[4];
#pragma unroll
        for (int m = 0; m < 4; m++) { uint4 t = As[cur][aidx[m]]; af[m] = __builtin_bit_cast(bf16x8, t); }
#pragma unroll
        for (int n = 0; n < 4; n++) { uint4 t = Bs[cur][bidx[n]]; bf[n] = __builtin_bit_cast(bf16x8, t); }
#pragma unroll
        for (int m = 0; m < 4; m++)
#pragma unroll
            for (int n = 0; n < 4; n++)
                acc[m][n] = __builtin_amdgcn_mfma_f32_16x16x32_bf16(af[m], bf[n], acc[m][n], 0, 0, 0);
        if (kt + 1 < KT) STORE(cur ^ 1);
        __syncthreads();
    }

    // epilogue: scale by routing weight, scatter-add to out
#pragma unroll
    for (int m = 0; m < 4; m++) {
#pragma unroll
        for (int r = 0; r < 4; r++) {
            const int lr = wm * 64 + m * 16 + ks * 4 + r;
            if (lr < valid) {
                const int tok = list_tok[e * TT + row0 + lr];
                const float wt = list_w[e * TT + row0 + lr];
                float* orow = out + (size_t)tok * HH;
#pragma unroll
                for (int n = 0; n < 4; n++) {
                    const int col = n0 + wn * 64 + n * 16 + l15;
                    atomicAdd(orow + col, acc[m][n][r] * wt);
                }
            }
        }
    }
}

extern "C" void kernel_launch(void* const* d_in, const int* in_sizes, int n_in,
                              void* d_out, int out_size, void* d_ws, size_t ws_size,
                              hipStream_t stream) {
    const float* x      = (const float*)d_in[0];
    const float* gating = (const float*)d_in[1];
    const float* w1     = (const float*)d_in[2];
    const float* w2     = (const float*)d_in[3];
    float* out = (float*)d_out;
    char* ws = (char*)d_ws;

    int*   list_tok = (int*)(ws + 0);              // 64 KB
    float* list_w   = (float*)(ws + (64 << 10));   // 64 KB
    int*   counts   = (int*)(ws + (128 << 10));    // 32 B
    int*   tk_idx   = (int*)(ws + (132 << 10));    // 16 KB
    float* tk_w     = (float*)(ws + (148 << 10));  // 16 KB
    __hip_bfloat16* hbuf = (__hip_bfloat16*)(ws + (1 << 20));  // 4096 x 5632 bf16 = 46.1 MB

    // xb (bf16 x, 8.4 MB) lives in d_out until gemm1 is done; memset before gemm2.
    __hip_bfloat16* xb = (__hip_bfloat16*)d_out;

    route_topk<<<TT / 256, 256, 0, stream>>>(gating, tk_idx, tk_w);
    build_lists<<<NE, 256, 0, stream>>>(tk_idx, tk_w, list_tok, list_w, counts);
    cvt_x<<<TT * HH / (256 * 8), 256, 0, stream>>>(x, xb);
    gemm1_swiglu<<<dim3(88, 128), 256, 0, stream>>>(xb, w1, list_tok, counts, hbuf);
    (void)hipMemsetAsync(d_out, 0, (size_t)TT * HH * sizeof(float), stream);
    gemm2_scatter<<<dim3(16, 128), 256, 0, stream>>>(hbuf, w2, list_tok, list_w, counts, out);
}

// Round 9
// 940.310 us; speedup vs baseline: 1.0600x; 1.0600x over previous
//
#include <hip/hip_runtime.h>
#include <hip/hip_bf16.h>

// MoE: T=2048, H=2048, I=5632, E=8, top-2 renormalized.
// route -> per-expert lists -> cvt x to bf16 (scratch = d_out) -> grouped GEMM1
// (x@w1^T fused SwiGLU, bf16 h to ws) -> memset out -> grouped GEMM2 (h@w2^T, *w, atomicAdd).
// R9: R3 structure/grids (best so far), but A-operands load DIRECTLY from global
// (bf16, L2/L3-resident) into regs, double-buffered one iter ahead; LDS stages B only
// (16KB/block -> more blocks/CU).  Lessons: launch_bounds tighter than (256,2) spills
// (R4/R5); deep pipelines didn't help (R6/R7); XCD/expert remap convoys L2 (R8).

#define TT 2048
#define HH 2048
#define II 5632
#define NE 8

using f32x4  = __attribute__((ext_vector_type(4))) float;
using bf16x8 = __attribute__((ext_vector_type(8))) short;

__device__ __forceinline__ uint32_t bfbits(float f) {
    __hip_bfloat16 h = __float2bfloat16(f);
    unsigned short u;
    __builtin_memcpy(&u, &h, 2);
    return (uint32_t)u;
}
__device__ __forceinline__ uint32_t pk2(float a, float b) {
    return bfbits(a) | (bfbits(b) << 16);
}
__device__ __forceinline__ uint4 pk8(const float4& a, const float4& b) {
    uint4 r;
    r.x = pk2(a.x, a.y); r.y = pk2(a.z, a.w);
    r.z = pk2(b.x, b.y); r.w = pk2(b.z, b.w);
    return r;
}

// ---------------- x -> bf16 ----------------
__global__ void cvt_x(const float* __restrict__ x, __hip_bfloat16* __restrict__ xb) {
    const int i = (blockIdx.x * 256 + threadIdx.x) * 8;
    float4 a = *(const float4*)(x + i);
    float4 b = *(const float4*)(x + i + 4);
    *(uint4*)(xb + i) = pk8(a, b);
}

// ---------------- routing ----------------
__global__ void route_topk(const float* __restrict__ gating,
                           int* __restrict__ tk_idx, float* __restrict__ tk_w) {
    int t = blockIdx.x * 256 + threadIdx.x;
    if (t >= TT) return;
    float g[NE];
#pragma unroll
    for (int e = 0; e < NE; e++) g[e] = gating[t * NE + e];
    int i0 = 0; float b0 = g[0];
#pragma unroll
    for (int e = 1; e < NE; e++) if (g[e] > b0) { b0 = g[e]; i0 = e; }
    int i1 = (i0 == 0) ? 1 : 0; float b1 = g[i1];
#pragma unroll
    for (int e = 0; e < NE; e++) if (e != i0 && g[e] > b1) { b1 = g[e]; i1 = e; }
    float ex = expf(b1 - b0);
    float w0 = 1.f / (1.f + ex);
    float w1 = ex / (1.f + ex);
    tk_idx[2 * t] = i0; tk_idx[2 * t + 1] = i1;
    tk_w[2 * t] = w0;  tk_w[2 * t + 1] = w1;
}

__global__ void build_lists(const int* __restrict__ tk_idx, const float* __restrict__ tk_w,
                            int* __restrict__ list_tok, float* __restrict__ list_w,
                            int* __restrict__ counts) {
    const int e = blockIdx.x;
    const int tid = threadIdx.x;
    int flag[8]; float wt[8];
    int cnt = 0;
#pragma unroll
    for (int j = 0; j < 8; j++) {
        int t = tid * 8 + j;
        int f = -1;
        if (tk_idx[2 * t] == e) f = 0;
        else if (tk_idx[2 * t + 1] == e) f = 1;
        flag[j] = f;
        wt[j] = (f >= 0) ? tk_w[2 * t + f] : 0.f;
        cnt += (f >= 0) ? 1 : 0;
    }
    __shared__ int s[256];
    s[tid] = cnt;
    __syncthreads();
    for (int d = 1; d < 256; d <<= 1) {
        int v = (tid >= d) ? s[tid - d] : 0;
        __syncthreads();
        s[tid] += v;
        __syncthreads();
    }
    int pos = s[tid] - cnt;
#pragma unroll
    for (int j = 0; j < 8; j++) {
        if (flag[j] >= 0) {
            list_tok[e * TT + pos] = tid * 8 + j;
            list_w[e * TT + pos] = wt[j];
            pos++;
        }
    }
    if (tid == 255) counts[e] = s[255];
}

// ---------------- GEMM1: h = SwiGLU(Xe @ w1[e]^T), tile 128(M) x 64(N of I), BK=32 ----------------
// LDS: Bg[2][256]+Bu[2][256] uint4 = 16KB.  A frags direct-from-global (reg dbuf).
__global__ __launch_bounds__(256, 2) void gemm1_swiglu(
    const __hip_bfloat16* __restrict__ xb, const float* __restrict__ w1,
    const int* __restrict__ list_tok, const int* __restrict__ counts,
    __hip_bfloat16* __restrict__ hbuf) {
    const int e = blockIdx.y >> 4;
    const int mt = blockIdx.y & 15;
    const int cnt = counts[e];
    const int row0 = mt * 128;
    if (row0 >= cnt) return;
    int off = 0;
#pragma unroll
    for (int i = 0; i < NE; i++) if (i < e) off += counts[i];
    const int valid = min(128, cnt - row0);
    const int n0 = blockIdx.x * 64;
    const int tid = threadIdx.x;

    __shared__ uint4 Bg[2][256];   // 64 rows x 32 bf16, swizzled 16B slots
    __shared__ uint4 Bu[2][256];

    // B staging: thread -> row ar0 (0..63), slot au (0..3)
    const int ar0 = tid >> 2, au = tid & 3;
    const float* gS = w1 + (size_t)e * (2 * II) * HH + (size_t)(n0 + ar0) * HH + au * 8;
    const float* uS = gS + (size_t)II * HH;
    const int bwi = ar0 * 4 + (au ^ ((ar0 >> 1) & 3));

    float4 rGa, rGb, rUa, rUb;
    auto LOADB = [&](int kt) {
        const int k = kt * 32;
        rGa = *(const float4*)(gS + k); rGb = *(const float4*)(gS + k + 4);
        rUa = *(const float4*)(uS + k); rUb = *(const float4*)(uS + k + 4);
    };
    auto STOREB = [&](int b) {
        Bg[b][bwi] = pk8(rGa, rGb);
        Bu[b][bwi] = pk8(rUa, rUb);
    };

    // wave grid 2x2, wave tile 64(M) x 32(N)
    const int lane = tid & 63;
    const int wv = tid >> 6;
    const int wm = wv >> 1, wn = wv & 1;
    const int l15 = lane & 15, ks = lane >> 4;

    // A fragment pointers: frag m covers rows wm*64+m*16+(0..15); lane reads its row at ks*8
    const __hip_bfloat16* aP[4];
#pragma unroll
    for (int m = 0; m < 4; m++) {
        int r = wm * 64 + m * 16 + l15;
        int tok = list_tok[e * TT + row0 + min(r, valid - 1)];
        aP[m] = xb + (size_t)tok * HH + ks * 8;
    }
    int bidx[2];
#pragma unroll
    for (int n = 0; n < 2; n++) { int c = wn * 32 + n * 16 + l15; bidx[n] = c * 4 + (ks ^ ((c >> 1) & 3)); }

    f32x4 accg[4][2], accu[4][2];
#pragma unroll
    for (int m = 0; m < 4; m++)
#pragma unroll
        for (int n = 0; n < 2; n++) { accg[m][n] = 0; accu[m][n] = 0; }

    uint4 aC[4], aN[4];
#pragma unroll
    for (int m = 0; m < 4; m++) aC[m] = *(const uint4*)(aP[m]);
    LOADB(0); STOREB(0);
    __syncthreads();

    const int KT = HH / 32;  // 64
#pragma unroll 2
    for (int kt = 0; kt < KT; ++kt) {
        const int cur = kt & 1;
        if (kt + 1 < KT) {
            LOADB(kt + 1);
#pragma unroll
            for (int m = 0; m < 4; m++) aN[m] = *(const uint4*)(aP[m] + (kt + 1) * 32);
        }
        bf16x8 gf[2], uf[2];
#pragma unroll
        for (int n = 0; n < 2; n++) {
            uint4 t = Bg[cur][bidx[n]]; gf[n] = __builtin_bit_cast(bf16x8, t);
            uint4 t2 = Bu[cur][bidx[n]]; uf[n] = __builtin_bit_cast(bf16x8, t2);
        }
#pragma unroll
        for (int m = 0; m < 4; m++) {
            bf16x8 af = __builtin_bit_cast(bf16x8, aC[m]);
#pragma unroll
            for (int n = 0; n < 2; n++) {
                accg[m][n] = __builtin_amdgcn_mfma_f32_16x16x32_bf16(af, gf[n], accg[m][n], 0, 0, 0);
                accu[m][n] = __builtin_amdgcn_mfma_f32_16x16x32_bf16(af, uf[n], accu[m][n], 0, 0, 0);
            }
        }
        if (kt + 1 < KT) {
            STOREB(cur ^ 1);
#pragma unroll
            for (int m = 0; m < 4; m++) aC[m] = aN[m];
        }
        __syncthreads();
    }

    // epilogue: h = silu(g)*u -> bf16
#pragma unroll
    for (int m = 0; m < 4; m++) {
#pragma unroll
        for (int r = 0; r < 4; r++) {
            const int lr = wm * 64 + m * 16 + ks * 4 + r;   // C row = (lane>>4)*4 + reg
            if (lr < valid) {
                __hip_bfloat16* hrow = hbuf + (size_t)(off + row0 + lr) * II;
#pragma unroll
                for (int n = 0; n < 2; n++) {
                    const int col = n0 + wn * 32 + n * 16 + l15;   // C col = lane&15
                    float g = accg[m][n][r], u = accu[m][n][r];
                    float h = g / (1.f + __expf(-g)) * u;
                    hrow[col] = __float2bfloat16(h);
                }
            }
        }
    }
}

// ---------------- GEMM2: out += (h @ w2[e]^T) * route_w, tile 128x128, BK=32 ----------------
// LDS: Bs[2][512] uint4 = 16KB.  A (hbuf rows, bf16) direct-from-global, reg dbuf.
__global__ __launch_bounds__(256, 2) void gemm2_scatter(
    const __hip_bfloat16* __restrict__ hbuf, const float* __restrict__ w2,
    const int* __restrict__ list_tok, const float* __restrict__ list_w,
    const int* __restrict__ counts, float* __restrict__ out) {
    const int e = blockIdx.y >> 4;
    const int mt = blockIdx.y & 15;
    const int cnt = counts[e];
    const int row0 = mt * 128;
    if (row0 >= cnt) return;
    int off = 0;
#pragma unroll
    for (int i = 0; i < NE; i++) if (i < e) off += counts[i];
    const int valid = min(128, cnt - row0);
    const int n0 = blockIdx.x * 128;
    const int tid = threadIdx.x;

    __shared__ uint4 Bs[2][512];   // 128 rows x 32 bf16

    const int ar0 = tid >> 2, au = tid & 3;
    const int ar1 = ar0 + 64;
    const float* bS0 = w2 + (size_t)e * HH * II + (size_t)(n0 + ar0) * II + au * 8;
    const float* bS1 = bS0 + (size_t)64 * II;
    const int bwi0 = ar0 * 4 + (au ^ ((ar0 >> 1) & 3));
    const int bwi1 = ar1 * 4 + (au ^ ((ar1 >> 1) & 3));

    float4 rB0a, rB0b, rB1a, rB1b;
    auto LOADB = [&](int kt) {
        const int k = kt * 32;
        rB0a = *(const float4*)(bS0 + k); rB0b = *(const float4*)(bS0 + k + 4);
        rB1a = *(const float4*)(bS1 + k); rB1b = *(const float4*)(bS1 + k + 4);
    };
    auto STOREB = [&](int b) {
        Bs[b][bwi0] = pk8(rB0a, rB0b);
        Bs[b][bwi1] = pk8(rB1a, rB1b);
    };

    // wave tile 64x64 (wave grid 2x2)
    const int lane = tid & 63;
    const int wv = tid >> 6;
    const int wm = wv >> 1, wn = wv & 1;
    const int l15 = lane & 15, ks = lane >> 4;

    const __hip_bfloat16* aP[4];
#pragma unroll
    for (int m = 0; m < 4; m++) {
        int r = wm * 64 + m * 16 + l15;
        aP[m] = hbuf + (size_t)(off + row0 + min(r, valid - 1)) * II + ks * 8;
    }
    int bidx[4];
#pragma unroll
    for (int n = 0; n < 4; n++) { int c = wn * 64 + n * 16 + l15; bidx[n] = c * 4 + (ks ^ ((c >> 1) & 3)); }

    f32x4 acc[4][4];
#pragma unroll
    for (int m = 0; m < 4; m++)
#pragma unroll
        for (int n = 0; n < 4; n++) acc[m][n] = 0;

    uint4 aC[4], aN[4];
#pragma unroll
    for (int m = 0; m < 4; m++) aC[m] = *(const uint4*)(aP[m]);
    LOADB(0); STOREB(0);
    __syncthreads();

    const int KT = II / 32;  // 176
#pragma unroll 2
    for (int kt = 0; kt < KT; ++kt) {
        const int cur = kt & 1;
        if (kt + 1 < KT) {
            LOADB(kt + 1);
#pragma unroll
            for (int m = 0; m < 4; m++) aN[m] = *(const uint4*)(aP[m] + (kt + 1) * 32);
        }
        bf16x8 bf[4];
#pragma unroll
        for (int n = 0; n < 4; n++) { uint4 t = Bs[cur][bidx[n]]; bf[n] = __builtin_bit_cast(bf16x8, t); }
#pragma unroll
        for (int m = 0; m < 4; m++) {
            bf16x8 af = __builtin_bit_cast(bf16x8, aC[m]);
#pragma unroll
            for (int n = 0; n < 4; n++)
                acc[m][n] = __builtin_amdgcn_mfma_f32_16x16x32_bf16(af, bf[n], acc[m][n], 0, 0, 0);
        }
        if (kt + 1 < KT) {
            STOREB(cur ^ 1);
#pragma unroll
            for (int m = 0; m < 4; m++) aC[m] = aN[m];
        }
        __syncthreads();
    }

    // epilogue: scale by routing weight, scatter-add to out
#pragma unroll
    for (int m = 0; m < 4; m++) {
#pragma unroll
        for (int r = 0; r < 4; r++) {
            const int lr = wm * 64 + m * 16 + ks * 4 + r;
            if (lr < valid) {
                const int tok = list_tok[e * TT + row0 + lr];
                const float wt = list_w[e * TT + row0 + lr];
                float* orow = out + (size_t)tok * HH;
#pragma unroll
                for (int n = 0; n < 4; n++) {
                    const int col = n0 + wn * 64 + n * 16 + l15;
                    atomicAdd(orow + col, acc[m][n][r] * wt);
                }
            }
        }
    }
}

extern "C" void kernel_launch(void* const* d_in, const int* in_sizes, int n_in,
                              void* d_out, int out_size, void* d_ws, size_t ws_size,
                              hipStream_t stream) {
    const float* x      = (const float*)d_in[0];
    const float* gating = (const float*)d_in[1];
    const float* w1     = (const float*)d_in[2];
    const float* w2     = (const float*)d_in[3];
    float* out = (float*)d_out;
    char* ws = (char*)d_ws;

    int*   list_tok = (int*)(ws + 0);              // 64 KB
    float* list_w   = (float*)(ws + (64 << 10));   // 64 KB
    int*   counts   = (int*)(ws + (128 << 10));    // 32 B
    int*   tk_idx   = (int*)(ws + (132 << 10));    // 16 KB
    float* tk_w     = (float*)(ws + (148 << 10));  // 16 KB
    __hip_bfloat16* hbuf = (__hip_bfloat16*)(ws + (1 << 20));  // 4096 x 5632 bf16 = 46.1 MB

    // xb (bf16 x, 8.4 MB) lives in d_out until gemm1 is done; memset before gemm2.
    __hip_bfloat16* xb = (__hip_bfloat16*)d_out;

    route_topk<<<TT / 256, 256, 0, stream>>>(gating, tk_idx, tk_w);
    build_lists<<<NE, 256, 0, stream>>>(tk_idx, tk_w, list_tok, list_w, counts);
    cvt_x<<<TT * HH / (256 * 8), 256, 0, stream>>>(x, xb);
    gemm1_swiglu<<<dim3(II / 64, NE * 16), 256, 0, stream>>>(xb, w1, list_tok, counts, hbuf);
    (void)hipMemsetAsync(d_out, 0, (size_t)TT * HH * sizeof(float), stream);
    gemm2_scatter<<<dim3(HH / 128, NE * 16), 256, 0, stream>>>(hbuf, w2, list_tok, list_w, counts, out);
}

// Round 10
// 735.443 us; speedup vs baseline: 1.3553x; 1.2786x over previous
//
#include <hip/hip_runtime.h>
#include <hip/hip_bf16.h>

// MoE: T=2048, H=2048, I=5632, E=8, top-2 renormalized.
// route -> lists -> cvt x to bf16 (scratch=d_out) -> grouped GEMM1 (x@w1^T SwiGLU -> bf16 h)
// -> memset out -> grouped GEMM2 (h@w2^T * w, atomicAdd).
// R10: occupancy attack. gemm1: A via global_load_lds (pre-swizzled source, linear LDS),
// B f32->bf16 reg roundtrip, launch_bounds(256,4) (target 64 VGPR + 64 AGPR = 128).
// gemm2: 512 thr / 8 waves, wave tile 64x32 -> acc 32 AGPR; A via global_load_lds.
// Lessons: asm-"memory"-clobber pipelines spill (R4/R5); deep pipelines null (R6/R7);
// XCD/expert remap convoys L2 (R8); occupancy was register-file-bound at 3 waves/SIMD.

#define TT 2048
#define HH 2048
#define II 5632
#define NE 8

using f32x4  = __attribute__((ext_vector_type(4))) float;
using bf16x8 = __attribute__((ext_vector_type(8))) short;

__device__ __forceinline__ uint32_t bfbits(float f) {
    __hip_bfloat16 h = __float2bfloat16(f);
    unsigned short u;
    __builtin_memcpy(&u, &h, 2);
    return (uint32_t)u;
}
__device__ __forceinline__ uint32_t pk2(float a, float b) {
    return bfbits(a) | (bfbits(b) << 16);
}
__device__ __forceinline__ uint4 pk8(const float4& a, const float4& b) {
    uint4 r;
    r.x = pk2(a.x, a.y); r.y = pk2(a.z, a.w);
    r.z = pk2(b.x, b.y); r.w = pk2(b.z, b.w);
    return r;
}
__device__ __forceinline__ void gl16(const void* g, void* l) {
    __builtin_amdgcn_global_load_lds(
        (const __attribute__((address_space(1))) unsigned int*)g,
        (__attribute__((address_space(3))) unsigned int*)l, 16, 0, 0);
}

// ---------------- x -> bf16 ----------------
__global__ void cvt_x(const float* __restrict__ x, __hip_bfloat16* __restrict__ xb) {
    const int i = (blockIdx.x * 256 + threadIdx.x) * 8;
    float4 a = *(const float4*)(x + i);
    float4 b = *(const float4*)(x + i + 4);
    *(uint4*)(xb + i) = pk8(a, b);
}

// ---------------- routing ----------------
__global__ void route_topk(const float* __restrict__ gating,
                           int* __restrict__ tk_idx, float* __restrict__ tk_w) {
    int t = blockIdx.x * 256 + threadIdx.x;
    if (t >= TT) return;
    float g[NE];
#pragma unroll
    for (int e = 0; e < NE; e++) g[e] = gating[t * NE + e];
    int i0 = 0; float b0 = g[0];
#pragma unroll
    for (int e = 1; e < NE; e++) if (g[e] > b0) { b0 = g[e]; i0 = e; }
    int i1 = (i0 == 0) ? 1 : 0; float b1 = g[i1];
#pragma unroll
    for (int e = 0; e < NE; e++) if (e != i0 && g[e] > b1) { b1 = g[e]; i1 = e; }
    float ex = expf(b1 - b0);
    float w0 = 1.f / (1.f + ex);
    float w1 = ex / (1.f + ex);
    tk_idx[2 * t] = i0; tk_idx[2 * t + 1] = i1;
    tk_w[2 * t] = w0;  tk_w[2 * t + 1] = w1;
}

__global__ void build_lists(const int* __restrict__ tk_idx, const float* __restrict__ tk_w,
                            int* __restrict__ list_tok, float* __restrict__ list_w,
                            int* __restrict__ counts) {
    const int e = blockIdx.x;
    const int tid = threadIdx.x;
    int flag[8]; float wt[8];
    int cnt = 0;
#pragma unroll
    for (int j = 0; j < 8; j++) {
        int t = tid * 8 + j;
        int f = -1;
        if (tk_idx[2 * t] == e) f = 0;
        else if (tk_idx[2 * t + 1] == e) f = 1;
        flag[j] = f;
        wt[j] = (f >= 0) ? tk_w[2 * t + f] : 0.f;
        cnt += (f >= 0) ? 1 : 0;
    }
    __shared__ int s[256];
    s[tid] = cnt;
    __syncthreads();
    for (int d = 1; d < 256; d <<= 1) {
        int v = (tid >= d) ? s[tid - d] : 0;
        __syncthreads();
        s[tid] += v;
        __syncthreads();
    }
    int pos = s[tid] - cnt;
#pragma unroll
    for (int j = 0; j < 8; j++) {
        if (flag[j] >= 0) {
            list_tok[e * TT + pos] = tid * 8 + j;
            list_w[e * TT + pos] = wt[j];
            pos++;
        }
    }
    if (tid == 255) counts[e] = s[255];
}

// ---------------- GEMM1: h = SwiGLU(Xe @ w1[e]^T), tile 128(M) x 64(Ncols), BK=32 ----------------
// LDS: A(glds) 8KB x2 + Bg 4KB x2 + Bu 4KB x2 = 32KB.
__global__ __launch_bounds__(256, 4) void gemm1_swiglu(
    const __hip_bfloat16* __restrict__ xb, const float* __restrict__ w1,
    const int* __restrict__ list_tok, const int* __restrict__ counts,
    __hip_bfloat16* __restrict__ hbuf) {
    const int e = blockIdx.y >> 4;
    const int mt = blockIdx.y & 15;
    const int cnt = counts[e];
    const int row0 = mt * 128;
    if (row0 >= cnt) return;
    int off = 0;
#pragma unroll
    for (int i = 0; i < NE; i++) if (i < e) off += counts[i];
    const int valid = min(128, cnt - row0);
    const int n0 = blockIdx.x * 64;
    const int tid = threadIdx.x;
    const int w = tid >> 6, l = tid & 63;

    __shared__ uint4 As[2 * 512];   // [buf][row 0..127][slot 0..3], LDS-linear, src pre-swizzled
    __shared__ uint4 Bg[2][256];    // [buf][row 0..63][slot], XOR-swizzled on write+read
    __shared__ uint4 Bu[2][256];

    // A staging via global_load_lds: call c covers rows c*64 + w*16 + (l>>2)
    const char *aSrc0, *aSrc1;
    {
        int r0 = w * 16 + (l >> 2);
        int r1 = r0 + 64;
        int t0 = list_tok[e * TT + row0 + min(r0, valid - 1)];
        int t1 = list_tok[e * TT + row0 + min(r1, valid - 1)];
        int s0 = (l & 3) ^ ((r0 >> 1) & 3);
        int s1 = (l & 3) ^ ((r1 >> 1) & 3);
        aSrc0 = (const char*)(xb + (size_t)t0 * HH + s0 * 8);
        aSrc1 = (const char*)(xb + (size_t)t1 * HH + s1 * 8);
    }
    auto STAGEA = [&](int kt, int b) {
        char* ab = (char*)As + b * 8192 + w * 1024;
        gl16(aSrc0 + (size_t)kt * 64, ab);
        gl16(aSrc1 + (size_t)kt * 64, ab + 4096);
    };

    // B staging: thread -> row br (0..63), slot bu2 (0..3)
    const int br = tid >> 2, bu2 = tid & 3;
    const float* gS = w1 + (size_t)e * (2 * II) * HH + (size_t)(n0 + br) * HH + bu2 * 8;
    const float* uS = gS + (size_t)II * HH;
    const int bwi = br * 4 + (bu2 ^ ((br >> 1) & 3));

    float4 rGa, rGb, rUa, rUb;
    auto LOADB = [&](int kt) {
        const int k = kt * 32;
        rGa = *(const float4*)(gS + k); rGb = *(const float4*)(gS + k + 4);
        rUa = *(const float4*)(uS + k); rUb = *(const float4*)(uS + k + 4);
    };
    auto STOREB = [&](int b) {
        Bg[b][bwi] = pk8(rGa, rGb);
        Bu[b][bwi] = pk8(rUa, rUb);
    };

    // wave grid 2x2, wave tile 64(M) x 32(Ncols)
    const int wm = w >> 1, wn = w & 1;
    const int l15 = l & 15, ks = l >> 4;
    int aidx[4], bidx[2];
#pragma unroll
    for (int m = 0; m < 4; m++) { int r = wm * 64 + m * 16 + l15; aidx[m] = r * 4 + (ks ^ ((r >> 1) & 3)); }
#pragma unroll
    for (int n = 0; n < 2; n++) { int c = wn * 32 + n * 16 + l15; bidx[n] = c * 4 + (ks ^ ((c >> 1) & 3)); }

    f32x4 accg[4][2], accu[4][2];
#pragma unroll
    for (int m = 0; m < 4; m++)
#pragma unroll
        for (int n = 0; n < 2; n++) { accg[m][n] = 0; accu[m][n] = 0; }

    STAGEA(0, 0); LOADB(0); STOREB(0);
    __syncthreads();
    const int KT = HH / 32;  // 64
#pragma unroll 2
    for (int kt = 0; kt < KT; ++kt) {
        const int cur = kt & 1;
        if (kt + 1 < KT) {
            STAGEA(kt + 1, cur ^ 1);
            LOADB(kt + 1);
        }
        bf16x8 af[4], gf[2], uf[2];
        const uint4* Ab = As + cur * 512;
#pragma unroll
        for (int m = 0; m < 4; m++) { uint4 t = Ab[aidx[m]]; af[m] = __builtin_bit_cast(bf16x8, t); }
#pragma unroll
        for (int n = 0; n < 2; n++) {
            uint4 t = Bg[cur][bidx[n]]; gf[n] = __builtin_bit_cast(bf16x8, t);
            uint4 t2 = Bu[cur][bidx[n]]; uf[n] = __builtin_bit_cast(bf16x8, t2);
        }
#pragma unroll
        for (int m = 0; m < 4; m++)
#pragma unroll
            for (int n = 0; n < 2; n++) {
                accg[m][n] = __builtin_amdgcn_mfma_f32_16x16x32_bf16(af[m], gf[n], accg[m][n], 0, 0, 0);
                accu[m][n] = __builtin_amdgcn_mfma_f32_16x16x32_bf16(af[m], uf[n], accu[m][n], 0, 0, 0);
            }
        if (kt + 1 < KT) STOREB(cur ^ 1);
        __syncthreads();
    }

    // epilogue: h = silu(g)*u -> bf16
#pragma unroll
    for (int m = 0; m < 4; m++) {
#pragma unroll
        for (int r = 0; r < 4; r++) {
            const int lr = wm * 64 + m * 16 + ks * 4 + r;   // C row = (lane>>4)*4 + reg
            if (lr < valid) {
                __hip_bfloat16* hrow = hbuf + (size_t)(off + row0 + lr) * II;
#pragma unroll
                for (int n = 0; n < 2; n++) {
                    const int col = n0 + wn * 32 + n * 16 + l15;   // C col = lane&15
                    float g = accg[m][n][r], u = accu[m][n][r];
                    float h = g / (1.f + __expf(-g)) * u;
                    hrow[col] = __float2bfloat16(h);
                }
            }
        }
    }
}

// ---------------- GEMM2: out += (h @ w2[e]^T) * route_w, tile 128x128, BK=32, 512 thr / 8 waves ----
// Wave tile 64x32 -> acc 8 frags = 32 AGPR. LDS: A 8KB x2 + B 8KB x2 = 32KB.
__global__ __launch_bounds__(512, 4) void gemm2_scatter(
    const __hip_bfloat16* __restrict__ hbuf, const float* __restrict__ w2,
    const int* __restrict__ list_tok, const float* __restrict__ list_w,
    const int* __restrict__ counts, float* __restrict__ out) {
    const int e = blockIdx.y >> 4;
    const int mt = blockIdx.y & 15;
    const int cnt = counts[e];
    const int row0 = mt * 128;
    if (row0 >= cnt) return;
    int off = 0;
#pragma unroll
    for (int i = 0; i < NE; i++) if (i < e) off += counts[i];
    const int valid = min(128, cnt - row0);
    const int n0 = blockIdx.x * 128;
    const int tid = threadIdx.x;
    const int w = tid >> 6, l = tid & 63;   // 8 waves

    __shared__ uint4 As[2 * 512];   // 128 rows x 4 slot16 per buf
    __shared__ uint4 Bs[2][512];    // 128 rows x 4 slot16 per buf

    // A staging via global_load_lds: one call per wave covers rows w*16 + (l>>2)
    const char* aSrc;
    {
        int r = w * 16 + (l >> 2);
        int s = (l & 3) ^ ((r >> 1) & 3);
        aSrc = (const char*)(hbuf + (size_t)(off + row0 + min(r, valid - 1)) * II + s * 8);
    }
    auto STAGEA = [&](int kt, int b) {
        char* ab = (char*)As + b * 8192 + w * 1024;
        gl16(aSrc + (size_t)kt * 64, ab);
    };

    // B staging: thread -> row br (0..127), slot bu2 (0..3)
    const int br = tid >> 2, bu2 = tid & 3;
    const float* bS = w2 + (size_t)e * HH * II + (size_t)(n0 + br) * II + bu2 * 8;
    const int bwi = br * 4 + (bu2 ^ ((br >> 1) & 3));

    float4 rBa, rBb;
    auto LOADB = [&](int kt) {
        const int k = kt * 32;
        rBa = *(const float4*)(bS + k); rBb = *(const float4*)(bS + k + 4);
    };
    auto STOREB = [&](int b) {
        Bs[b][bwi] = pk8(rBa, rBb);
    };

    // wave grid 2(M) x 4(N); wave tile 64 x 32
    const int wm = w >> 2, wn = w & 3;
    const int l15 = l & 15, ks = l >> 4;
    int aidx[4], bidx[2];
#pragma unroll
    for (int m = 0; m < 4; m++) { int r = wm * 64 + m * 16 + l15; aidx[m] = r * 4 + (ks ^ ((r >> 1) & 3)); }
#pragma unroll
    for (int n = 0; n < 2; n++) { int c = wn * 32 + n * 16 + l15; bidx[n] = c * 4 + (ks ^ ((c >> 1) & 3)); }

    f32x4 acc[4][2];
#pragma unroll
    for (int m = 0; m < 4; m++)
#pragma unroll
        for (int n = 0; n < 2; n++) acc[m][n] = 0;

    STAGEA(0, 0); LOADB(0); STOREB(0);
    __syncthreads();
    const int KT = II / 32;  // 176
#pragma unroll 2
    for (int kt = 0; kt < KT; ++kt) {
        const int cur = kt & 1;
        if (kt + 1 < KT) {
            STAGEA(kt + 1, cur ^ 1);
            LOADB(kt + 1);
        }
        bf16x8 af[4], bf[2];
        const uint4* Ab = As + cur * 512;
#pragma unroll
        for (int m = 0; m < 4; m++) { uint4 t = Ab[aidx[m]]; af[m] = __builtin_bit_cast(bf16x8, t); }
#pragma unroll
        for (int n = 0; n < 2; n++) { uint4 t = Bs[cur][bidx[n]]; bf[n] = __builtin_bit_cast(bf16x8, t); }
#pragma unroll
        for (int m = 0; m < 4; m++)
#pragma unroll
            for (int n = 0; n < 2; n++)
                acc[m][n] = __builtin_amdgcn_mfma_f32_16x16x32_bf16(af[m], bf[n], acc[m][n], 0, 0, 0);
        if (kt + 1 < KT) STOREB(cur ^ 1);
        __syncthreads();
    }

    // epilogue: scale by routing weight, scatter-add
#pragma unroll
    for (int m = 0; m < 4; m++) {
#pragma unroll
        for (int r = 0; r < 4; r++) {
            const int lr = wm * 64 + m * 16 + ks * 4 + r;
            if (lr < valid) {
                const int tok = list_tok[e * TT + row0 + lr];
                const float wt = list_w[e * TT + row0 + lr];
                float* orow = out + (size_t)tok * HH;
#pragma unroll
                for (int n = 0; n < 2; n++) {
                    const int col = n0 + wn * 32 + n * 16 + l15;
                    atomicAdd(orow + col, acc[m][n][r] * wt);
                }
            }
        }
    }
}

extern "C" void kernel_launch(void* const* d_in, const int* in_sizes, int n_in,
                              void* d_out, int out_size, void* d_ws, size_t ws_size,
                              hipStream_t stream) {
    const float* x      = (const float*)d_in[0];
    const float* gating = (const float*)d_in[1];
    const float* w1     = (const float*)d_in[2];
    const float* w2     = (const float*)d_in[3];
    float* out = (float*)d_out;
    char* ws = (char*)d_ws;

    int*   list_tok = (int*)(ws + 0);              // 64 KB
    float* list_w   = (float*)(ws + (64 << 10));   // 64 KB
    int*   counts   = (int*)(ws + (128 << 10));    // 32 B
    int*   tk_idx   = (int*)(ws + (132 << 10));    // 16 KB
    float* tk_w     = (float*)(ws + (148 << 10));  // 16 KB
    __hip_bfloat16* hbuf = (__hip_bfloat16*)(ws + (1 << 20));  // 4096 x 5632 bf16 = 46.1 MB

    // xb (bf16 x, 8.4 MB) lives in d_out until gemm1 is done; memset before gemm2.
    __hip_bfloat16* xb = (__hip_bfloat16*)d_out;

    route_topk<<<TT / 256, 256, 0, stream>>>(gating, tk_idx, tk_w);
    build_lists<<<NE, 256, 0, stream>>>(tk_idx, tk_w, list_tok, list_w, counts);
    cvt_x<<<TT * HH / (256 * 8), 256, 0, stream>>>(x, xb);
    gemm1_swiglu<<<dim3(II / 64, NE * 16), 256, 0, stream>>>(xb, w1, list_tok, counts, hbuf);
    (void)hipMemsetAsync(d_out, 0, (size_t)TT * HH * sizeof(float), stream);
    gemm2_scatter<<<dim3(HH / 128, NE * 16), 512, 0, stream>>>(hbuf, w2, list_tok, list_w, counts, out);
}

// Round 11
// 689.779 us; speedup vs baseline: 1.4451x; 1.0662x over previous
//
#include <hip/hip_runtime.h>
#include <hip/hip_bf16.h>

// MoE: T=2048, H=2048, I=5632, E=8, top-2 renormalized.
// route -> lists -> cvt x bf16 (scratch=d_out) -> GEMM1 (x@w1^T SwiGLU -> bf16 h)
// -> memset out -> GEMM2 (h@w2^T * w, atomicAdd).
// R11: L3-traffic attack. 512-thread blocks, taller tiles at constant 64-AGPR/wave:
// gemm1 256Mx64cols (B rereads 4->2), gemm2 256Mx128N (B rereads 4->2).
// A via global_load_lds (pre-swizzled source, linear LDS); B f32->bf16 reg roundtrip;
// plain dbuf + __syncthreads (proven spill-free).  Lessons: asm-fence pipelines spill
// (R4/R5); deep pipelines null (R6/R7); XCD clustering convoys (R8); occupancy not
// the binder (R10: 41% occ, same dur) -> all-structures-equal 470us = traffic-bound.

#define TT 2048
#define HH 2048
#define II 5632
#define NE 8

using f32x4  = __attribute__((ext_vector_type(4))) float;
using bf16x8 = __attribute__((ext_vector_type(8))) short;

__device__ __forceinline__ uint32_t bfbits(float f) {
    __hip_bfloat16 h = __float2bfloat16(f);
    unsigned short u;
    __builtin_memcpy(&u, &h, 2);
    return (uint32_t)u;
}
__device__ __forceinline__ uint32_t pk2(float a, float b) {
    return bfbits(a) | (bfbits(b) << 16);
}
__device__ __forceinline__ uint4 pk8(const float4& a, const float4& b) {
    uint4 r;
    r.x = pk2(a.x, a.y); r.y = pk2(a.z, a.w);
    r.z = pk2(b.x, b.y); r.w = pk2(b.z, b.w);
    return r;
}
__device__ __forceinline__ void gl16(const void* g, void* l) {
    __builtin_amdgcn_global_load_lds(
        (const __attribute__((address_space(1))) unsigned int*)g,
        (__attribute__((address_space(3))) unsigned int*)l, 16, 0, 0);
}

// ---------------- x -> bf16 ----------------
__global__ void cvt_x(const float* __restrict__ x, __hip_bfloat16* __restrict__ xb) {
    const int i = (blockIdx.x * 256 + threadIdx.x) * 8;
    float4 a = *(const float4*)(x + i);
    float4 b = *(const float4*)(x + i + 4);
    *(uint4*)(xb + i) = pk8(a, b);
}

// ---------------- routing ----------------
__global__ void route_topk(const float* __restrict__ gating,
                           int* __restrict__ tk_idx, float* __restrict__ tk_w) {
    int t = blockIdx.x * 256 + threadIdx.x;
    if (t >= TT) return;
    float g[NE];
#pragma unroll
    for (int e = 0; e < NE; e++) g[e] = gating[t * NE + e];
    int i0 = 0; float b0 = g[0];
#pragma unroll
    for (int e = 1; e < NE; e++) if (g[e] > b0) { b0 = g[e]; i0 = e; }
    int i1 = (i0 == 0) ? 1 : 0; float b1 = g[i1];
#pragma unroll
    for (int e = 0; e < NE; e++) if (e != i0 && g[e] > b1) { b1 = g[e]; i1 = e; }
    float ex = expf(b1 - b0);
    float w0 = 1.f / (1.f + ex);
    float w1 = ex / (1.f + ex);
    tk_idx[2 * t] = i0; tk_idx[2 * t + 1] = i1;
    tk_w[2 * t] = w0;  tk_w[2 * t + 1] = w1;
}

__global__ void build_lists(const int* __restrict__ tk_idx, const float* __restrict__ tk_w,
                            int* __restrict__ list_tok, float* __restrict__ list_w,
                            int* __restrict__ counts) {
    const int e = blockIdx.x;
    const int tid = threadIdx.x;
    int flag[8]; float wt[8];
    int cnt = 0;
#pragma unroll
    for (int j = 0; j < 8; j++) {
        int t = tid * 8 + j;
        int f = -1;
        if (tk_idx[2 * t] == e) f = 0;
        else if (tk_idx[2 * t + 1] == e) f = 1;
        flag[j] = f;
        wt[j] = (f >= 0) ? tk_w[2 * t + f] : 0.f;
        cnt += (f >= 0) ? 1 : 0;
    }
    __shared__ int s[256];
    s[tid] = cnt;
    __syncthreads();
    for (int d = 1; d < 256; d <<= 1) {
        int v = (tid >= d) ? s[tid - d] : 0;
        __syncthreads();
        s[tid] += v;
        __syncthreads();
    }
    int pos = s[tid] - cnt;
#pragma unroll
    for (int j = 0; j < 8; j++) {
        if (flag[j] >= 0) {
            list_tok[e * TT + pos] = tid * 8 + j;
            list_w[e * TT + pos] = wt[j];
            pos++;
        }
    }
    if (tid == 255) counts[e] = s[255];
}

// ---------------- GEMM1: tile 256(M) x 64 I-cols, BK=32, 512 thr / 8 waves ----------------
// Wave grid 4Mx2N, wave tile 64x32cols, dual acc = 16 frags = 64 AGPR.
// LDS: A 16KB x2 (glds) + B(g+u 128 rows) 8KB x2 = 48KB.
__global__ __launch_bounds__(512, 4) void gemm1_swiglu(
    const __hip_bfloat16* __restrict__ xb, const float* __restrict__ w1,
    const int* __restrict__ list_tok, const int* __restrict__ counts,
    __hip_bfloat16* __restrict__ hbuf) {
    const int e = blockIdx.y >> 3;
    const int mt = blockIdx.y & 7;
    const int cnt = counts[e];
    const int row0 = mt * 256;
    if (row0 >= cnt) return;
    int off = 0;
#pragma unroll
    for (int i = 0; i < NE; i++) if (i < e) off += counts[i];
    const int valid = min(256, cnt - row0);
    const int n0 = blockIdx.x * 64;
    const int tid = threadIdx.x;
    const int w = tid >> 6, l = tid & 63;   // 8 waves

    __shared__ uint4 As[2 * 1024];  // [buf][row 0..255][slot 0..3] linear; src pre-swizzled
    __shared__ uint4 Bs[2][512];    // [buf][row 0..127][slot] (g rows 0..63, u rows 64..127)

    // A staging: call c covers rows c*128 + w*16 + (l>>2)
    const char *aSrc0, *aSrc1;
    {
        int r0 = w * 16 + (l >> 2);
        int r1 = r0 + 128;
        int t0 = list_tok[e * TT + row0 + min(r0, valid - 1)];
        int t1 = list_tok[e * TT + row0 + min(r1, valid - 1)];
        int s0 = (l & 3) ^ ((r0 >> 1) & 3);
        int s1 = (l & 3) ^ ((r1 >> 1) & 3);
        aSrc0 = (const char*)(xb + (size_t)t0 * HH + s0 * 8);
        aSrc1 = (const char*)(xb + (size_t)t1 * HH + s1 * 8);
    }
    auto STAGEA = [&](int kt, int b) {
        char* ab = (char*)As + b * 16384 + w * 1024;
        gl16(aSrc0 + (size_t)kt * 64, ab);
        gl16(aSrc1 + (size_t)kt * 64, ab + 8192);
    };

    // B staging: thread -> row br (0..127), slot bu2 (0..3); br<64 -> g, else u
    const int br = tid >> 2, bu2 = tid & 3;
    const float* bSrc;
    {
        const float* base = w1 + (size_t)e * (2 * II) * HH;
        int r = (br < 64) ? (n0 + br) : (II + n0 + (br - 64));
        bSrc = base + (size_t)r * HH + bu2 * 8;
    }
    const int bwi = br * 4 + (bu2 ^ ((br >> 1) & 3));

    float4 rBa, rBb;
    auto LOADB = [&](int kt) {
        const int k = kt * 32;
        rBa = *(const float4*)(bSrc + k); rBb = *(const float4*)(bSrc + k + 4);
    };
    auto STOREB = [&](int b) { Bs[b][bwi] = pk8(rBa, rBb); };

    // wave grid 4M x 2N; wave tile 64 rows x 32 cols
    const int wm = w >> 1, wn = w & 1;
    const int l15 = l & 15, ks = l >> 4;
    int aidx[4], bgidx[2], buidx[2];
#pragma unroll
    for (int m = 0; m < 4; m++) { int r = wm * 64 + m * 16 + l15; aidx[m] = r * 4 + (ks ^ ((r >> 1) & 3)); }
#pragma unroll
    for (int n = 0; n < 2; n++) {
        int cg = wn * 32 + n * 16 + l15;       // g row in Bs
        int cu = cg + 64;                       // u row in Bs
        bgidx[n] = cg * 4 + (ks ^ ((cg >> 1) & 3));
        buidx[n] = cu * 4 + (ks ^ ((cu >> 1) & 3));
    }

    f32x4 accg[4][2], accu[4][2];
#pragma unroll
    for (int m = 0; m < 4; m++)
#pragma unroll
        for (int n = 0; n < 2; n++) { accg[m][n] = 0; accu[m][n] = 0; }

    STAGEA(0, 0); LOADB(0); STOREB(0);
    __syncthreads();
    const int KT = HH / 32;  // 64
#pragma unroll 2
    for (int kt = 0; kt < KT; ++kt) {
        const int cur = kt & 1;
        if (kt + 1 < KT) {
            STAGEA(kt + 1, cur ^ 1);
            LOADB(kt + 1);
        }
        bf16x8 gf[2], uf[2];
#pragma unroll
        for (int n = 0; n < 2; n++) {
            uint4 t = Bs[cur][bgidx[n]]; gf[n] = __builtin_bit_cast(bf16x8, t);
            uint4 t2 = Bs[cur][buidx[n]]; uf[n] = __builtin_bit_cast(bf16x8, t2);
        }
        const uint4* Ab = As + cur * 1024;
#pragma unroll
        for (int m = 0; m < 4; m++) {
            uint4 t = Ab[aidx[m]];
            bf16x8 af = __builtin_bit_cast(bf16x8, t);
#pragma unroll
            for (int n = 0; n < 2; n++) {
                accg[m][n] = __builtin_amdgcn_mfma_f32_16x16x32_bf16(af, gf[n], accg[m][n], 0, 0, 0);
                accu[m][n] = __builtin_amdgcn_mfma_f32_16x16x32_bf16(af, uf[n], accu[m][n], 0, 0, 0);
            }
        }
        if (kt + 1 < KT) STOREB(cur ^ 1);
        __syncthreads();
    }

    // epilogue: h = silu(g)*u -> bf16
#pragma unroll
    for (int m = 0; m < 4; m++) {
#pragma unroll
        for (int r = 0; r < 4; r++) {
            const int lr = wm * 64 + m * 16 + ks * 4 + r;
            if (lr < valid) {
                __hip_bfloat16* hrow = hbuf + (size_t)(off + row0 + lr) * II;
#pragma unroll
                for (int n = 0; n < 2; n++) {
                    const int col = n0 + wn * 32 + n * 16 + l15;
                    float g = accg[m][n][r], u = accu[m][n][r];
                    float h = g / (1.f + __expf(-g)) * u;
                    hrow[col] = __float2bfloat16(h);
                }
            }
        }
    }
}

// ---------------- GEMM2: tile 256(M) x 128(N), BK=32, 512 thr / 8 waves ----------------
// Wave grid 2Mx4N, wave tile 128x32, acc[8][2] = 16 frags = 64 AGPR.
// LDS: A 16KB x2 (glds) + B 8KB x2 = 48KB.
__global__ __launch_bounds__(512, 4) void gemm2_scatter(
    const __hip_bfloat16* __restrict__ hbuf, const float* __restrict__ w2,
    const int* __restrict__ list_tok, const float* __restrict__ list_w,
    const int* __restrict__ counts, float* __restrict__ out) {
    const int e = blockIdx.y >> 3;
    const int mt = blockIdx.y & 7;
    const int cnt = counts[e];
    const int row0 = mt * 256;
    if (row0 >= cnt) return;
    int off = 0;
#pragma unroll
    for (int i = 0; i < NE; i++) if (i < e) off += counts[i];
    const int valid = min(256, cnt - row0);
    const int n0 = blockIdx.x * 128;
    const int tid = threadIdx.x;
    const int w = tid >> 6, l = tid & 63;

    __shared__ uint4 As[2 * 1024];  // 256 rows x 4 slots per buf
    __shared__ uint4 Bs[2][512];    // 128 rows x 4 slots per buf

    const char *aSrc0, *aSrc1;
    {
        int r0 = w * 16 + (l >> 2);
        int r1 = r0 + 128;
        int s0 = (l & 3) ^ ((r0 >> 1) & 3);
        int s1 = (l & 3) ^ ((r1 >> 1) & 3);
        aSrc0 = (const char*)(hbuf + (size_t)(off + row0 + min(r0, valid - 1)) * II + s0 * 8);
        aSrc1 = (const char*)(hbuf + (size_t)(off + row0 + min(r1, valid - 1)) * II + s1 * 8);
    }
    auto STAGEA = [&](int kt, int b) {
        char* ab = (char*)As + b * 16384 + w * 1024;
        gl16(aSrc0 + (size_t)kt * 64, ab);
        gl16(aSrc1 + (size_t)kt * 64, ab + 8192);
    };

    const int br = tid >> 2, bu2 = tid & 3;
    const float* bSrc = w2 + (size_t)e * HH * II + (size_t)(n0 + br) * II + bu2 * 8;
    const int bwi = br * 4 + (bu2 ^ ((br >> 1) & 3));

    float4 rBa, rBb;
    auto LOADB = [&](int kt) {
        const int k = kt * 32;
        rBa = *(const float4*)(bSrc + k); rBb = *(const float4*)(bSrc + k + 4);
    };
    auto STOREB = [&](int b) { Bs[b][bwi] = pk8(rBa, rBb); };

    // wave grid 2M x 4N; wave tile 128 rows x 32 cols
    const int wm = w >> 2, wn = w & 3;
    const int l15 = l & 15, ks = l >> 4;
    int aidx[8], bidx[2];
#pragma unroll
    for (int m = 0; m < 8; m++) { int r = wm * 128 + m * 16 + l15; aidx[m] = r * 4 + (ks ^ ((r >> 1) & 3)); }
#pragma unroll
    for (int n = 0; n < 2; n++) { int c = wn * 32 + n * 16 + l15; bidx[n] = c * 4 + (ks ^ ((c >> 1) & 3)); }

    f32x4 acc[8][2];
#pragma unroll
    for (int m = 0; m < 8; m++)
#pragma unroll
        for (int n = 0; n < 2; n++) acc[m][n] = 0;

    STAGEA(0, 0); LOADB(0); STOREB(0);
    __syncthreads();
    const int KT = II / 32;  // 176
#pragma unroll 2
    for (int kt = 0; kt < KT; ++kt) {
        const int cur = kt & 1;
        if (kt + 1 < KT) {
            STAGEA(kt + 1, cur ^ 1);
            LOADB(kt + 1);
        }
        bf16x8 bf[2];
#pragma unroll
        for (int n = 0; n < 2; n++) { uint4 t = Bs[cur][bidx[n]]; bf[n] = __builtin_bit_cast(bf16x8, t); }
        const uint4* Ab = As + cur * 1024;
#pragma unroll
        for (int m = 0; m < 8; m++) {
            uint4 t = Ab[aidx[m]];
            bf16x8 af = __builtin_bit_cast(bf16x8, t);
#pragma unroll
            for (int n = 0; n < 2; n++)
                acc[m][n] = __builtin_amdgcn_mfma_f32_16x16x32_bf16(af, bf[n], acc[m][n], 0, 0, 0);
        }
        if (kt + 1 < KT) STOREB(cur ^ 1);
        __syncthreads();
    }

    // epilogue: scale by routing weight, scatter-add
#pragma unroll
    for (int m = 0; m < 8; m++) {
#pragma unroll
        for (int r = 0; r < 4; r++) {
            const int lr = wm * 128 + m * 16 + ks * 4 + r;
            if (lr < valid) {
                const int tok = list_tok[e * TT + row0 + lr];
                const float wt = list_w[e * TT + row0 + lr];
                float* orow = out + (size_t)tok * HH;
#pragma unroll
                for (int n = 0; n < 2; n++) {
                    const int col = n0 + wn * 32 + n * 16 + l15;
                    atomicAdd(orow + col, acc[m][n][r] * wt);
                }
            }
        }
    }
}

extern "C" void kernel_launch(void* const* d_in, const int* in_sizes, int n_in,
                              void* d_out, int out_size, void* d_ws, size_t ws_size,
                              hipStream_t stream) {
    const float* x      = (const float*)d_in[0];
    const float* gating = (const float*)d_in[1];
    const float* w1     = (const float*)d_in[2];
    const float* w2     = (const float*)d_in[3];
    float* out = (float*)d_out;
    char* ws = (char*)d_ws;

    int*   list_tok = (int*)(ws + 0);              // 64 KB
    float* list_w   = (float*)(ws + (64 << 10));   // 64 KB
    int*   counts   = (int*)(ws + (128 << 10));    // 32 B
    int*   tk_idx   = (int*)(ws + (132 << 10));    // 16 KB
    float* tk_w     = (float*)(ws + (148 << 10));  // 16 KB
    __hip_bfloat16* hbuf = (__hip_bfloat16*)(ws + (1 << 20));  // 4096 x 5632 bf16 = 46.1 MB

    // xb (bf16 x, 8.4 MB) lives in d_out until gemm1 is done; memset before gemm2.
    __hip_bfloat16* xb = (__hip_bfloat16*)d_out;

    route_topk<<<TT / 256, 256, 0, stream>>>(gating, tk_idx, tk_w);
    build_lists<<<NE, 256, 0, stream>>>(tk_idx, tk_w, list_tok, list_w, counts);
    cvt_x<<<TT * HH / (256 * 8), 256, 0, stream>>>(x, xb);
    gemm1_swiglu<<<dim3(II / 64, NE * 8), 512, 0, stream>>>(xb, w1, list_tok, counts, hbuf);
    (void)hipMemsetAsync(d_out, 0, (size_t)TT * HH * sizeof(float), stream);
    gemm2_scatter<<<dim3(HH / 128, NE * 8), 512, 0, stream>>>(hbuf, w2, list_tok, list_w, counts, out);
}